// Round 1
// baseline (2217.478 us; speedup 1.0000x reference)
//
#include <hip/hip_runtime.h>
#include <hip/hip_bf16.h>
#include <math.h>

#define N_NODES 100000
#define N_EDGES 500000
#define MEM 128
#define IN_DIM 256
#define TIMEF 64
#define EDGEF 64
#define D_EDGE 128
#define EPSILON 0.1f
#define GAMMA 0.1f
#define SCALE 0.08838834764831845f  // 1/sqrt(128)

#define NPB 8  // nodes per block (100000 % 8 == 0 -> 12500 blocks)
#define EPB 8  // edges per block (500000 % 8 == 0 -> 62500 blocks)

// order-preserving float->uint encoding for atomicMax-based segment max
__device__ __forceinline__ unsigned int encf(float f) {
    unsigned int u = __float_as_uint(f);
    return (u & 0x80000000u) ? ~u : (u | 0x80000000u);
}
__device__ __forceinline__ float decf(unsigned int k) {
    unsigned int u = (k & 0x80000000u) ? (k & 0x7FFFFFFFu) : ~k;
    return __uint_as_float(u);
}

__global__ void k_init(unsigned int* amax_enc, float* denom) {
    int i = blockIdx.x * blockDim.x + threadIdx.x;
    if (i < N_NODES) {
        amax_enc[i] = 0x007FFFFFu;  // encf(-inf)
        denom[i] = 0.0f;
    }
}

__global__ void k_prepA(const float* __restrict__ W_anti, float* __restrict__ Abuf) {
    int idx = blockIdx.x * blockDim.x + threadIdx.x;  // 16384 total
    int m = idx >> 7, d = idx & 127;
    float a = W_anti[m * 128 + d] - W_anti[d * 128 + m];
    if (m == d) a -= GAMMA;
    Abuf[idx] = a;
}

// h = x@W_enc^T + b_enc ; q,k,v = h@W^T + b  (fused, NPB nodes per block)
__global__ __launch_bounds__(128) void k_node_proj(
    const float* __restrict__ x,
    const float* __restrict__ W_enc, const float* __restrict__ b_enc,
    const float* __restrict__ Wq, const float* __restrict__ bq,
    const float* __restrict__ Wk, const float* __restrict__ bk,
    const float* __restrict__ Wv, const float* __restrict__ bv,
    float* __restrict__ h, float* __restrict__ q,
    float* __restrict__ k, float* __restrict__ v)
{
    __shared__ float xs[NPB][IN_DIM];
    __shared__ float hs[NPB][MEM];
    const int m = threadIdx.x;       // 0..127 output dim
    const int n0 = blockIdx.x * NPB;

    for (int j = 0; j < NPB; j++) {
        const float* xr = x + (size_t)(n0 + j) * IN_DIM;
        xs[j][m] = xr[m];
        xs[j][m + 128] = xr[m + 128];
    }
    __syncthreads();

    // h row
    float acc[NPB];
    float be = b_enc[m];
    for (int j = 0; j < NPB; j++) acc[j] = be;
    const float4* W4 = (const float4*)(W_enc + (size_t)m * IN_DIM);
    for (int d4 = 0; d4 < IN_DIM / 4; d4++) {
        float4 w = W4[d4];
        int d = d4 * 4;
        for (int j = 0; j < NPB; j++)
            acc[j] += w.x * xs[j][d] + w.y * xs[j][d + 1] + w.z * xs[j][d + 2] + w.w * xs[j][d + 3];
    }
    for (int j = 0; j < NPB; j++) {
        h[(size_t)(n0 + j) * MEM + m] = acc[j];
        hs[j][m] = acc[j];
    }
    __syncthreads();

#define PROJ(W, B, OUT)                                                          \
    {                                                                            \
        float a2[NPB];                                                           \
        float bb = B[m];                                                         \
        for (int j = 0; j < NPB; j++) a2[j] = bb;                                \
        const float4* Wb = (const float4*)(W + (size_t)m * MEM);                 \
        for (int d4 = 0; d4 < MEM / 4; d4++) {                                   \
            float4 w = Wb[d4];                                                   \
            int d = d4 * 4;                                                      \
            for (int j = 0; j < NPB; j++)                                        \
                a2[j] += w.x * hs[j][d] + w.y * hs[j][d + 1] + w.z * hs[j][d + 2] \
                       + w.w * hs[j][d + 3];                                     \
        }                                                                        \
        for (int j = 0; j < NPB; j++) OUT[(size_t)(n0 + j) * MEM + m] = a2[j];   \
    }
    PROJ(Wq, bq, q)
    PROJ(Wk, bk, k)
    PROJ(Wv, bv, v)
#undef PROJ
}

// shared edge-attr build + e_proj compute, used by both edge passes
#define EDGE_PREAMBLE                                                            \
    __shared__ float ea[EPB][D_EDGE];                                            \
    __shared__ int s_src[EPB], s_dst[EPB];                                       \
    __shared__ float s_rel[EPB];                                                 \
    const int m = threadIdx.x;                                                   \
    const size_t e0 = (size_t)blockIdx.x * EPB;                                  \
    if (m < EPB) {                                                               \
        size_t e = e0 + m;                                                       \
        int srcn = ei[e];                                                        \
        int dstn = ei[N_EDGES + e];                                              \
        s_src[m] = srcn;                                                         \
        s_dst[m] = dstn;                                                         \
        s_rel[m] = fabsf(last_update[srcn] - t[e]);                              \
    }                                                                            \
    __syncthreads();                                                             \
    {                                                                            \
        float wt = (m >= 64) ? w_time[m - 64] : 0.f;                             \
        float bt = (m >= 64) ? b_time[m - 64] : 0.f;                             \
        for (int j = 0; j < EPB; j++) {                                          \
            float val;                                                           \
            if (m < 64) val = msg[(e0 + j) * EDGEF + m];                         \
            else        val = cosf(s_rel[j] * wt + bt);                          \
            ea[j][m] = val;                                                      \
        }                                                                        \
    }                                                                            \
    __syncthreads();                                                             \
    float ep[EPB];                                                               \
    for (int j = 0; j < EPB; j++) ep[j] = 0.f;                                   \
    {                                                                            \
        const float4* We4 = (const float4*)(We + (size_t)m * D_EDGE);            \
        for (int d4 = 0; d4 < D_EDGE / 4; d4++) {                                \
            float4 w = We4[d4];                                                  \
            int d = d4 * 4;                                                      \
            for (int j = 0; j < EPB; j++)                                        \
                ep[j] += w.x * ea[j][d] + w.y * ea[j][d + 1]                     \
                       + w.z * ea[j][d + 2] + w.w * ea[j][d + 3];                \
        }                                                                        \
    }

__global__ __launch_bounds__(128) void k_edge_alpha(
    const int* __restrict__ ei, const float* __restrict__ last_update,
    const float* __restrict__ t, const float* __restrict__ msg,
    const float* __restrict__ w_time, const float* __restrict__ b_time,
    const float* __restrict__ We,
    const float* __restrict__ q, const float* __restrict__ k,
    float* __restrict__ alpha, unsigned int* __restrict__ amax_enc)
{
    EDGE_PREAMBLE
    __shared__ float red[EPB][2];
    float p[EPB];
    for (int j = 0; j < EPB; j++) {
        float ke = k[(size_t)s_src[j] * MEM + m] + ep[j];
        float qv = q[(size_t)s_dst[j] * MEM + m];
        p[j] = qv * ke;
    }
    int lane = m & 63, wave = m >> 6;
    for (int j = 0; j < EPB; j++) {
        float vs = p[j];
        for (int off = 32; off > 0; off >>= 1) vs += __shfl_down(vs, off, 64);
        if (lane == 0) red[j][wave] = vs;
    }
    __syncthreads();
    if (m < EPB) {
        float a = (red[m][0] + red[m][1]) * SCALE;
        alpha[e0 + m] = a;
        atomicMax(&amax_enc[s_dst[m]], encf(a));
    }
}

__global__ __launch_bounds__(128) void k_edge_agg(
    const int* __restrict__ ei, const float* __restrict__ last_update,
    const float* __restrict__ t, const float* __restrict__ msg,
    const float* __restrict__ w_time, const float* __restrict__ b_time,
    const float* __restrict__ We,
    const float* __restrict__ v, const float* __restrict__ alpha,
    const unsigned int* __restrict__ amax_enc,
    float* __restrict__ agg, float* __restrict__ denom)
{
    EDGE_PREAMBLE
    __shared__ float s_ex[EPB];
    if (m < EPB) {
        float am = decf(amax_enc[s_dst[m]]);
        float ex = expf(alpha[e0 + m] - am);
        s_ex[m] = ex;
        atomicAdd(&denom[s_dst[m]], ex);
    }
    __syncthreads();
    for (int j = 0; j < EPB; j++) {
        float ve = v[(size_t)s_src[j] * MEM + m] + ep[j];
        atomicAdd(&agg[(size_t)s_dst[j] * MEM + m], s_ex[j] * ve);
    }
}

__global__ __launch_bounds__(128) void k_final(
    const float* __restrict__ h, const float* __restrict__ agg,
    const float* __restrict__ denom, const float* __restrict__ Abuf,
    const float* __restrict__ b_anti, float* __restrict__ out)
{
    __shared__ float hsh[NPB][MEM];
    const int m = threadIdx.x;
    const int n0 = blockIdx.x * NPB;
    for (int j = 0; j < NPB; j++) hsh[j][m] = h[(size_t)(n0 + j) * MEM + m];
    __syncthreads();
    float acc[NPB];
    float ba = b_anti[m];
    for (int j = 0; j < NPB; j++) {
        float dn = denom[n0 + j] + 1e-16f;
        acc[j] = ba + agg[(size_t)(n0 + j) * MEM + m] / dn;
    }
    const float4* A4 = (const float4*)(Abuf + (size_t)m * MEM);
    for (int d4 = 0; d4 < MEM / 4; d4++) {
        float4 w = A4[d4];
        int d = d4 * 4;
        for (int j = 0; j < NPB; j++)
            acc[j] += w.x * hsh[j][d] + w.y * hsh[j][d + 1] + w.z * hsh[j][d + 2] + w.w * hsh[j][d + 3];
    }
    for (int j = 0; j < NPB; j++) {
        float hv = hsh[j][m] + EPSILON * tanhf(acc[j]);
        out[(size_t)(n0 + j) * MEM + m] = tanhf(hv);
    }
}

extern "C" void kernel_launch(void* const* d_in, const int* in_sizes, int n_in,
                              void* d_out, int out_size, void* d_ws, size_t ws_size,
                              hipStream_t stream) {
    const float* x          = (const float*)d_in[0];
    const float* last_update= (const float*)d_in[1];
    const int*   ei         = (const int*)  d_in[2];
    const float* t          = (const float*)d_in[3];
    const float* msg        = (const float*)d_in[4];
    const float* w_time     = (const float*)d_in[5];
    const float* b_time     = (const float*)d_in[6];
    const float* W_enc      = (const float*)d_in[7];
    const float* b_enc      = (const float*)d_in[8];
    const float* Wq         = (const float*)d_in[9];
    const float* bq         = (const float*)d_in[10];
    const float* Wk         = (const float*)d_in[11];
    const float* bk         = (const float*)d_in[12];
    const float* Wv         = (const float*)d_in[13];
    const float* bv         = (const float*)d_in[14];
    const float* We         = (const float*)d_in[15];
    const float* W_anti     = (const float*)d_in[16];
    const float* b_anti     = (const float*)d_in[17];
    float* out = (float*)d_out;

    // workspace layout (floats)
    float* ws = (float*)d_ws;
    size_t nm = (size_t)N_NODES * MEM;
    float* h     = ws;                 // N*128
    float* q     = h + nm;             // N*128
    float* k     = q + nm;             // N*128
    float* v     = k + nm;             // N*128
    float* agg   = v + nm;             // N*128
    float* alpha = agg + nm;           // E
    float* amaxf = alpha + N_EDGES;    // N (uint encoded)
    float* denom = amaxf + N_NODES;    // N
    float* Abuf  = denom + N_NODES;    // 128*128
    unsigned int* amax_enc = (unsigned int*)amaxf;

    hipMemsetAsync(agg, 0, nm * sizeof(float), stream);
    k_init<<<(N_NODES + 255) / 256, 256, 0, stream>>>(amax_enc, denom);
    k_prepA<<<(MEM * MEM) / 256, 256, 0, stream>>>(W_anti, Abuf);

    k_node_proj<<<N_NODES / NPB, 128, 0, stream>>>(
        x, W_enc, b_enc, Wq, bq, Wk, bk, Wv, bv, h, q, k, v);

    k_edge_alpha<<<N_EDGES / EPB, 128, 0, stream>>>(
        ei, last_update, t, msg, w_time, b_time, We, q, k, alpha, amax_enc);

    k_edge_agg<<<N_EDGES / EPB, 128, 0, stream>>>(
        ei, last_update, t, msg, w_time, b_time, We, v, alpha, amax_enc, agg, denom);

    k_final<<<N_NODES / NPB, 128, 0, stream>>>(h, agg, denom, Abuf, b_anti, out);
}